// Round 1
// baseline (125.000 us; speedup 1.0000x reference)
//
#include <hip/hip_runtime.h>

// YOLO v1 loss, fused single-pass reduction.
// Shapes: output/target (8192, 7, 7, 30) f32, grid_mask_obj (8192,7,7) i32.
// Out: scalar f32 loss.

constexpr int   S_      = 7;
constexpr float IMG_    = 448.0f;
constexpr float CELLW_  = 1.0f / 7.0f;
constexpr float INV_BS_ = 1.0f / 8192.0f;

__global__ __launch_bounds__(256) void yolo_loss_kernel(
    const float* __restrict__ outp, const float* __restrict__ tgtp,
    const int* __restrict__ maskp, float* __restrict__ res, int ncell)
{
    int idx = blockIdx.x * blockDim.x + threadIdx.x;
    float acc = 0.0f;

    if (idx < ncell) {
        // ---- load 30 floats per input (120 B, 8B-aligned for every cell) ----
        const float2* po = reinterpret_cast<const float2*>(outp) + (size_t)idx * 15;
        const float2* pt = reinterpret_cast<const float2*>(tgtp) + (size_t)idx * 15;
        float o[30], t[30];
#pragma unroll
        for (int k = 0; k < 15; ++k) {
            float2 v = po[k]; o[2*k] = v.x; o[2*k+1] = v.y;
            float2 w = pt[k]; t[2*k] = w.x; t[2*k+1] = w.y;
        }
        int m = maskp[idx];

        int rem = idx % 49;           // cell within image: rem/7 = row(y), rem%7 = col(x)
        float gx = (float)(rem % 7) * CELLW_;
        float gy = (float)(rem / 7) * CELLW_;

        // ---- decode target box 0 to pixel corners ----
        float tx = (t[0] * CELLW_ + gx) * IMG_;
        float ty = (t[1] * CELLW_ + gy) * IMG_;
        float tw = t[2] * IMG_, th = t[3] * IMG_;
        float tx1 = tx - tw * 0.5f, tx2 = tx + tw * 0.5f;
        float ty1 = ty - th * 0.5f, ty2 = ty + th * 0.5f;
        float area_t = (tx2 - tx1) * (ty2 - ty1);

        // ---- IoU of each output box vs target box 0 ----
        float iou[2];
#pragma unroll
        for (int b = 0; b < 2; ++b) {
            float b0 = (b == 0) ? o[0] : o[5];
            float b1 = (b == 0) ? o[1] : o[6];
            float b2 = (b == 0) ? o[2] : o[7];
            float b3 = (b == 0) ? o[3] : o[8];
            float x = (b0 * CELLW_ + gx) * IMG_;
            float y = (b1 * CELLW_ + gy) * IMG_;
            float w = b2 * IMG_, h = b3 * IMG_;
            float x1 = x - w * 0.5f, x2 = x + w * 0.5f;
            float y1 = y - h * 0.5f, y2 = y + h * 0.5f;
            float iw = fmaxf(fminf(x2, tx2) - fmaxf(x1, tx1), 0.0f);
            float ih = fmaxf(fminf(y2, ty2) - fmaxf(y1, ty1), 0.0f);
            float inter = iw * ih;
            float area_o = (x2 - x1) * (y2 - y1);
            iou[b] = inter / (area_o + area_t - inter);
        }

        // jnp.argmax tie -> first index
        int   max_id  = (iou[1] > iou[0]) ? 1 : 0;
        float max_iou = fmaxf(iou[0], iou[1]);

        // ---- obj-cell terms (selection indices are compile-time via ternaries) ----
        // box_id_reg = obj ? max_id : 0  (we only use it when obj=1 -> max_id)
        float so0 = max_id ? o[5] : o[0];
        float so1 = max_id ? o[6] : o[1];
        float so2 = max_id ? o[7] : o[2];
        float so3 = max_id ? o[8] : o[3];
        float st0 = max_id ? t[5] : t[0];
        float st1 = max_id ? t[6] : t[1];
        float st2 = max_id ? t[7] : t[2];
        float st3 = max_id ? t[8] : t[3];

        float dxy0 = so0 - st0, dxy1 = so1 - st1;
        float xy_loss = dxy0 * dxy0 + dxy1 * dxy1;

        float dwh0 = sqrtf(so2) - sqrtf(st2);
        float dwh1 = sqrtf(so3) - sqrtf(st3);
        float wh_loss = dwh0 * dwh0 + dwh1 * dwh1;

        // box_id_conf = (obj && max_iou>0) ? max_id : 0; sel_iou = onehot[id_conf]*max_iou
        int   id_conf = (max_iou > 0.0f) ? max_id : 0;
        float sel_c   = id_conf ? o[9] : o[4];
        float sel_iou = (id_conf == max_id) ? max_iou : 0.0f;
        float dcf     = sel_c - sel_iou;
        float c_obj   = dcf * dcf;

        float cls = 0.0f;
#pragma unroll
        for (int k = 10; k < 30; ++k) {
            float d = o[k] - t[k];
            cls += d * d;
        }

        // ---- noobj term ----
        float dn0 = o[4] - t[4], dn1 = o[9] - t[9];
        float c_noobj = dn0 * dn0 + dn1 * dn1;

        acc = m ? (5.0f * (xy_loss + wh_loss) + c_obj + cls)
                : (0.5f * c_noobj);
    }

    // ---- wave (64-lane) reduction ----
#pragma unroll
    for (int off = 32; off > 0; off >>= 1)
        acc += __shfl_down(acc, off);

    __shared__ float wsum[4];
    int lane = threadIdx.x & 63;
    int wid  = threadIdx.x >> 6;
    if (lane == 0) wsum[wid] = acc;
    __syncthreads();
    if (threadIdx.x == 0) {
        float bsum = wsum[0] + wsum[1] + wsum[2] + wsum[3];
        atomicAdd(res, bsum * INV_BS_);
    }
}

extern "C" void kernel_launch(void* const* d_in, const int* in_sizes, int n_in,
                              void* d_out, int out_size, void* d_ws, size_t ws_size,
                              hipStream_t stream) {
    const float* outp = (const float*)d_in[0];
    const float* tgtp = (const float*)d_in[1];
    const int*   mask = (const int*)d_in[2];
    float*       res  = (float*)d_out;

    int ncell = in_sizes[2];  // 8192*7*7 = 401408

    // d_out is re-poisoned to 0xAA before every replay; zero it on-stream
    // (hipMemsetAsync is graph-capture safe).
    hipMemsetAsync(d_out, 0, sizeof(float), stream);

    int threads = 256;
    int blocks  = (ncell + threads - 1) / threads;
    yolo_loss_kernel<<<blocks, threads, 0, stream>>>(outp, tgtp, mask, res, ncell);
}